// Round 6
// baseline (389.922 us; speedup 1.0000x reference)
//
#include <hip/hip_runtime.h>
#include <hip/hip_bf16.h>

typedef unsigned short u16;

#define T_SEQ 2048
#define NTOK 4096          // B*T
#define D_MODEL 2560
#define NQKV 4096          // H*Hd + 2*G*Hd
#define WIN 1024
#define ATTN_SCALE 0.0625f // 256^-0.5
#define SMAX 17.0f         // |score*scale| <= 16.13 (RMSNorm => |q|=|k|=16)
#define KROW 264           // padded Ks row (u16): 528B stride -> conflict-free
#define VROW 40            // padded Vs/Ps row (u16): 80B stride -> 2-way max

typedef __attribute__((ext_vector_type(8))) short bf16x8;
typedef __attribute__((ext_vector_type(8))) unsigned short u16x8;
typedef __attribute__((ext_vector_type(4))) float f32x4;

__device__ __forceinline__ float bf2f(u16 u) {
  union { unsigned int i; float f; } c; c.i = ((unsigned int)u) << 16; return c.f;
}
__device__ __forceinline__ u16 f2bf(float f) {
  __hip_bfloat16 h = __float2bfloat16(f);
  return __builtin_bit_cast(u16, h);
}
__device__ __forceinline__ u16x8 load8f(const float* p) {
  float4 a = *(const float4*)p;
  float4 b = *(const float4*)(p + 4);
  u16x8 r;
  r[0] = f2bf(a.x); r[1] = f2bf(a.y); r[2] = f2bf(a.z); r[3] = f2bf(a.w);
  r[4] = f2bf(b.x); r[5] = f2bf(b.y); r[6] = f2bf(b.z); r[7] = f2bf(b.w);
  return r;
}
__device__ __forceinline__ void gload_lds16(const u16* g, u16* l) {
  __builtin_amdgcn_global_load_lds(
      (const __attribute__((address_space(1))) void*)g,
      (__attribute__((address_space(3))) void*)l, 16, 0, 0);
}

// ---------------- x f32 -> bf16 bulk convert -------------------------------
__global__ __launch_bounds__(256) void cvt_f32_bf16(
    const float* __restrict__ in, u16* __restrict__ out) {
  size_t i = ((size_t)blockIdx.x * 256 + threadIdx.x) * 8;
  *(u16x8*)(out + i) = load8f(in + i);
}

// ---------------- weight transpose: out[n][k] = bf16(in[k][n]), in f32 -----
__global__ __launch_bounds__(256) void transpose_w(
    const float* __restrict__ in, u16* __restrict__ out, int K, int N) {
  __shared__ u16 tile[64][65];
  int kb = blockIdx.y * 64, nb = blockIdx.x * 64;
  int t = threadIdx.x;
  int c4 = (t & 15) * 4;
  int r0 = t >> 4;
#pragma unroll
  for (int i = 0; i < 4; ++i) {
    int r = r0 + i * 16;
    float4 v = *(const float4*)(in + (size_t)(kb + r) * N + nb + c4);
    tile[r][c4] = f2bf(v.x); tile[r][c4 + 1] = f2bf(v.y);
    tile[r][c4 + 2] = f2bf(v.z); tile[r][c4 + 3] = f2bf(v.w);
  }
  __syncthreads();
#pragma unroll
  for (int i = 0; i < 4; ++i) {
    int n = r0 + i * 16;
    ushort4 v;
    v.x = tile[c4 + 0][n];
    v.y = tile[c4 + 1][n];
    v.z = tile[c4 + 2][n];
    v.w = tile[c4 + 3][n];
    *(ushort4*)(out + (size_t)(nb + n) * K + kb + c4) = v;
  }
}

// ---------------- V transpose: Vt[(b*4+g)][dim][t] = qkv[b,t][3072+g*256+dim]
__global__ __launch_bounds__(256) void v_transpose(
    const u16* __restrict__ qkv, u16* __restrict__ Vt) {
  int bg = blockIdx.z; int b = bg >> 2, g = bg & 3;
  __shared__ u16 tile[64][65];
  int tb = blockIdx.y * 64, db = blockIdx.x * 64;
  const u16* in = qkv + (size_t)(b * T_SEQ) * NQKV + 3072 + g * 256;
  u16* out = Vt + (size_t)bg * 256 * T_SEQ;
  int t = threadIdx.x;
  int c4 = (t & 15) * 4;
  int r0 = t >> 4;
#pragma unroll
  for (int i = 0; i < 4; ++i) {
    int r = r0 + i * 16;   // token within tile
    ushort4 v = *(const ushort4*)(in + (size_t)(tb + r) * NQKV + db + c4);
    tile[r][c4] = v.x; tile[r][c4 + 1] = v.y; tile[r][c4 + 2] = v.z; tile[r][c4 + 3] = v.w;
  }
  __syncthreads();
#pragma unroll
  for (int i = 0; i < 4; ++i) {
    int n = r0 + i * 16;   // dim within tile
    ushort4 v;
    v.x = tile[c4 + 0][n];
    v.y = tile[c4 + 1][n];
    v.z = tile[c4 + 2][n];
    v.w = tile[c4 + 3][n];
    *(ushort4*)(out + (size_t)(db + n) * T_SEQ + tb + c4) = v;
  }
}

// ============================================================================
// gemm_fat: 256x256 tile, 256 threads (4 FAT waves, 2M x 2N; 128x128 output
// per wave).  LDS read traffic per K-step drops 96KB -> 64KB per CU (each
// A/B half read 2x instead of 4x/2x mix) -- removes the LDS-bandwidth wall
// that pinned the 8-wave variants at ~40% MfmaUtil (rounds 1-4: three
// schedule variants all ~89us, 0 conflicts, HBM 18%, VALU 17%).
// acc 8x8xf32x4 = 256 VGPR -> __launch_bounds__(256,1): 1 wave/SIMD, 512-VGPR
// budget; 64 independent accumulators keep the matrix pipe issue-bound.
// Ring-of-4 BK=32 LDS (128 KiB dynamic), XOR-swizzled layout, linear
// global_load_lds dest + inverse-swizzled global source, counted vmcnt,
// bijective XCD-chunked block swizzle.
//
//   iter s, phase A: read aF[0..7]+bF[0..3] [slot s]; stage A(s+3); bar;
//                    lgkm0; 32 MFMA (n0..3); bar
//   iter s, phase B: read bF[4..7] [slot s]; stage B(s+3); bar;
//                    lgkm0; 32 MFMA (n4..7); vmcnt(16|8|0); bar
// vmcnt ledger: 8 vmem instr/iter (stageA=4, stageB=4).  Outstanding at the
// end-of-iter-s wait: s+1(8), s+2(8), s+3(8) = 24 -> vmcnt(16) drains s+1.
// Tail: s==NK-3 -> vmcnt(8); s==NK-2 -> vmcnt(0).  Prologue stages 0,1,2
// (24 instr), vmcnt(16) -> slot 0 resident.
// Slot-write races: identical barrier ledger to the verified v4 (slot-s reads
// drain before iter-s final barrier; stage(s+3) writes slot (s-1)&3 whose
// last reads drained one iter earlier).
// ============================================================================
template <int WC>
__global__ __launch_bounds__(256, 1) void gemm_fat(
    const u16* __restrict__ A, int lda, const u16* __restrict__ Bt, int ldb,
    void* __restrict__ C, int ldc, int K) {
  extern __shared__ ulong2 LDSraw[];
  u16* SA = (u16*)LDSraw;          // [4][8192]
  u16* SB = SA + 32768;            // [4][8192]
  const int tid = threadIdx.x;
  const int wave = tid >> 6, lane = tid & 63;
  const int quad = lane >> 4, l16 = lane & 15;
  // bijective XCD-chunked swizzle (nwg % 8 == 0 at both call sites)
  const int gx = gridDim.x;
  const int orig = blockIdx.y * gx + blockIdx.x;
  const int cpx = (gx * gridDim.y) >> 3;
  const int swz = (orig & 7) * cpx + (orig >> 3);
  const int mblk = (swz / gx) * 256, nblk = (swz % gx) * 256;
  const int wm = (wave >> 1) * 128, wn = (wave & 1) * 128;

  // staging: unit u = i*256+tid (16B units of a 16 KiB subtile), i=0..3
  //  dest (linear): elem offset u*8; wave-uniform base (u>>6 = i*4+wave)
  //  source: undo swizzle: hi3=(u&7)^((u>>3)&7); row=(u>>3)*2|(hi3>>2);
  //          col elems=(hi3&3)*8
  const u16* srcA[4]; const u16* srcB[4];
  int ldsOff[4];
#pragma unroll
  for (int i = 0; i < 4; ++i) {
    int u = i * 256 + tid;
    int hi3 = (u & 7) ^ ((u >> 3) & 7);
    int r = ((u >> 3) << 1) | (hi3 >> 2);
    int cbe = (hi3 & 3) << 3;
    srcA[i] = A + (size_t)(mblk + r) * lda + cbe;
    srcB[i] = Bt + (size_t)(nblk + r) * ldb + cbe;
    ldsOff[i] = (u >> 6) << 9;     // wave-uniform
  }
  // fragment-read base (elems within a slot); valid since wm>>1, wn>>1, t*8
  // are multiples of 8 (wm,wn in {0,128}).
  const int unit = ((((l16 & 1) << 2) | quad) ^ ((l16 >> 1) & 7)) << 3;
  const int base_a = ((wm >> 1) + (l16 >> 1)) * 64 + unit;
  const int base_b = ((wn >> 1) + (l16 >> 1)) * 64 + unit;
  const int NK = K >> 5;
  f32x4 acc[8][8] = {};

  auto stageA = [&](int s) {
    u16* d = SA + (s & 3) * 8192;
#pragma unroll
    for (int i = 0; i < 4; ++i) gload_lds16(srcA[i] + s * 32, d + ldsOff[i]);
  };
  auto stageB = [&](int s) {
    u16* d = SB + (s & 3) * 8192;
#pragma unroll
    for (int i = 0; i < 4; ++i) gload_lds16(srcB[i] + s * 32, d + ldsOff[i]);
  };

  // prologue: subtiles 0,1,2 (24 instrs); vmcnt(16) -> subtile 0 complete
  stageA(0); stageB(0); stageA(1); stageB(1); stageA(2); stageB(2);
  asm volatile("s_waitcnt vmcnt(16)" ::: "memory");
  __builtin_amdgcn_s_barrier();
  asm volatile("" ::: "memory");

  for (int s = 0; s < NK; ++s) {
    const u16* sa = SA + (s & 3) * 8192;
    const u16* sb = SB + (s & 3) * 8192;
    bf16x8 aF[8], bF[8];
    // ---- phase A: read aF[0..7]+bF[0..3]; stage A(s+3); MFMA n0..3 ----
#pragma unroll
    for (int t = 0; t < 8; ++t) aF[t] = *(const bf16x8*)(sa + base_a + t * 512);
#pragma unroll
    for (int t = 0; t < 4; ++t) bF[t] = *(const bf16x8*)(sb + base_b + t * 512);
    if (s + 3 < NK) stageA(s + 3);
    asm volatile("" ::: "memory");
    __builtin_amdgcn_s_barrier();
    asm volatile("s_waitcnt lgkmcnt(0)" ::: "memory");
    __builtin_amdgcn_sched_barrier(0);
    __builtin_amdgcn_s_setprio(1);
#pragma unroll
    for (int n = 0; n < 4; ++n)
#pragma unroll
      for (int m = 0; m < 8; ++m)
        acc[m][n] = __builtin_amdgcn_mfma_f32_16x16x32_bf16(aF[m], bF[n], acc[m][n], 0, 0, 0);
    __builtin_amdgcn_s_setprio(0);
    asm volatile("" ::: "memory");
    __builtin_amdgcn_s_barrier();
    asm volatile("" ::: "memory");
    // ---- phase B: read bF[4..7]; stage B(s+3); MFMA n4..7 ----
#pragma unroll
    for (int t = 4; t < 8; ++t) bF[t] = *(const bf16x8*)(sb + base_b + t * 512);
    if (s + 3 < NK) stageB(s + 3);
    asm volatile("" ::: "memory");
    __builtin_amdgcn_s_barrier();
    asm volatile("s_waitcnt lgkmcnt(0)" ::: "memory");
    __builtin_amdgcn_sched_barrier(0);
    __builtin_amdgcn_s_setprio(1);
#pragma unroll
    for (int n = 4; n < 8; ++n)
#pragma unroll
      for (int m = 0; m < 8; ++m)
        acc[m][n] = __builtin_amdgcn_mfma_f32_16x16x32_bf16(aF[m], bF[n], acc[m][n], 0, 0, 0);
    __builtin_amdgcn_s_setprio(0);
    if (s < NK - 3)       asm volatile("s_waitcnt vmcnt(16)" ::: "memory");
    else if (s == NK - 3) asm volatile("s_waitcnt vmcnt(8)" ::: "memory");
    else if (s == NK - 2) asm volatile("s_waitcnt vmcnt(0)" ::: "memory");
    if (s + 1 < NK) {
      asm volatile("" ::: "memory");
      __builtin_amdgcn_s_barrier();
      asm volatile("" ::: "memory");
    }
  }
#pragma unroll
  for (int m = 0; m < 8; ++m)
#pragma unroll
    for (int n = 0; n < 8; ++n)
#pragma unroll
      for (int r = 0; r < 4; ++r) {
        int row = mblk + wm + m * 16 + quad * 4 + r;
        int col = nblk + wn + n * 16 + l16;
        if constexpr (WC)
          ((float*)C)[(size_t)row * ldc + col] = acc[m][n][r];
        else
          ((u16*)C)[(size_t)row * ldc + col] = f2bf(acc[m][n][r]);
      }
}

// ---------------- fast GEMM (m97): bf16 A/Bt, global_load_lds staging -------
// (retained for the fallback path)
template <int WC>
__global__ __launch_bounds__(256, 2) void gemm_fast(
    const u16* __restrict__ A, int lda, const u16* __restrict__ Bt, int ldb,
    void* __restrict__ C, int ldc, int K) {
  __shared__ __align__(16) u16 As[128 * 32];
  __shared__ __align__(16) u16 Bs[128 * 32];
  const int tid = threadIdx.x;
  const int wave = tid >> 6, lane = tid & 63;
  const int quad = lane >> 4, l16 = lane & 15;
  const int mblk = blockIdx.y * 128, nblk = blockIdx.x * 128;
  const int wm = (wave >> 1) * 64, wn = (wave & 1) * 64;
  f32x4 acc[4][4] = {};
  const int c0 = wave * 2;
  for (int k0 = 0; k0 < K; k0 += 32) {
#pragma unroll
    for (int i = 0; i < 2; ++i) {
      int c = c0 + i;
      int flat = c * 64 + lane;       // 16B unit 0..511
      int row = flat >> 2;
      int kb = (flat & 3) * 8;
      gload_lds16(A + (size_t)(mblk + row) * lda + k0 + kb, As + c * 512);
      gload_lds16(Bt + (size_t)(nblk + row) * ldb + k0 + kb, Bs + c * 512);
    }
    __syncthreads();
    bf16x8 aF[4], bF[4];
#pragma unroll
    for (int t = 0; t < 4; ++t) {
      aF[t] = *(const bf16x8*)(As + (wm + t * 16 + l16) * 32 + quad * 8);
      bF[t] = *(const bf16x8*)(Bs + (wn + t * 16 + l16) * 32 + quad * 8);
    }
#pragma unroll
    for (int tm = 0; tm < 4; ++tm)
#pragma unroll
      for (int tn = 0; tn < 4; ++tn)
        acc[tm][tn] = __builtin_amdgcn_mfma_f32_16x16x32_bf16(aF[tm], bF[tn], acc[tm][tn], 0, 0, 0);
    __syncthreads();
  }
#pragma unroll
  for (int tm = 0; tm < 4; ++tm)
#pragma unroll
    for (int tn = 0; tn < 4; ++tn)
#pragma unroll
      for (int r = 0; r < 4; ++r) {
        int row = mblk + wm + tm * 16 + quad * 4 + r;
        int col = nblk + wn + tn * 16 + l16;
        if constexpr (WC)
          ((float*)C)[(size_t)row * ldc + col] = acc[tm][tn][r];
        else
          ((u16*)C)[(size_t)row * ldc + col] = f2bf(acc[tm][tn][r]);
      }
}

// ---------------- fallback GEMM: f32 A, manual staging ----------------------
__global__ __launch_bounds__(256, 2) void gemm_f32a(
    const float* __restrict__ A, int lda, const u16* __restrict__ Bt, int ldb,
    u16* __restrict__ C, int ldc, int K) {
  __shared__ __align__(16) u16 As[128 * 32];
  __shared__ __align__(16) u16 Bs[128 * 32];
  const int tid = threadIdx.x;
  const int wave = tid >> 6, lane = tid & 63;
  const int quad = lane >> 4, l16 = lane & 15;
  const int mblk = blockIdx.y * 128, nblk = blockIdx.x * 128;
  const int wm = (wave >> 1) * 64, wn = (wave & 1) * 64;
  f32x4 acc[4][4] = {};
  for (int k0 = 0; k0 < K; k0 += 32) {
#pragma unroll
    for (int i = 0; i < 2; ++i) {
      int u = i * 256 + tid;
      int row = u >> 2;
      int kb = (u & 3) * 8;
      *(u16x8*)(As + row * 32 + kb) = load8f(A + (size_t)(mblk + row) * lda + k0 + kb);
      *(u16x8*)(Bs + row * 32 + kb) = *(const u16x8*)(Bt + (size_t)(nblk + row) * ldb + k0 + kb);
    }
    __syncthreads();
    bf16x8 aF[4], bF[4];
#pragma unroll
    for (int t = 0; t < 4; ++t) {
      aF[t] = *(const bf16x8*)(As + (wm + t * 16 + l16) * 32 + quad * 8);
      bF[t] = *(const bf16x8*)(Bs + (wn + t * 16 + l16) * 32 + quad * 8);
    }
#pragma unroll
    for (int tm = 0; tm < 4; ++tm)
#pragma unroll
      for (int tn = 0; tn < 4; ++tn)
        acc[tm][tn] = __builtin_amdgcn_mfma_f32_16x16x32_bf16(aF[tm], bF[tn], acc[tm][tn], 0, 0, 0);
    __syncthreads();
  }
#pragma unroll
  for (int tm = 0; tm < 4; ++tm)
#pragma unroll
    for (int tn = 0; tn < 4; ++tn)
#pragma unroll
      for (int r = 0; r < 4; ++r) {
        int row = mblk + wm + tm * 16 + quad * 4 + r;
        int col = nblk + wn + tn * 16 + l16;
        C[(size_t)row * ldc + col] = f2bf(acc[tm][tn][r]);
      }
}

// ---------------- RMSNorm on q (8 heads) and k (4 groups), in place ---------
__global__ __launch_bounds__(256) void rmsnorm_qk(
    u16* __restrict__ qkv, const float* __restrict__ q_scale,
    const float* __restrict__ k_scale) {
  int wv = blockIdx.x * 4 + (threadIdx.x >> 6);
  int lane = threadIdx.x & 63;
  int token = wv / 12, j = wv - token * 12;
  const float* sc = (j < 8) ? q_scale : k_scale;
  int col = (j < 8) ? j * 256 : 2048 + (j - 8) * 256;
  u16* p = qkv + (size_t)token * NQKV + col;
  int d = lane * 4;
  ushort4 raw = *(const ushort4*)(p + d);
  float x0 = bf2f(raw.x), x1 = bf2f(raw.y), x2 = bf2f(raw.z), x3 = bf2f(raw.w);
  float sum = x0 * x0 + x1 * x1 + x2 * x2 + x3 * x3;
#pragma unroll
  for (int m = 1; m < 64; m <<= 1) sum += __shfl_xor(sum, m, 64);
  float r = rsqrtf(sum * (1.0f / 256.0f) + 1e-6f);
  float4 sv = *(const float4*)(sc + d);
  ushort4 o;
  o.x = f2bf(x0 * r * (1.0f + sv.x));
  o.y = f2bf(x1 * r * (1.0f + sv.y));
  o.z = f2bf(x2 * r * (1.0f + sv.z));
  o.w = f2bf(x3 * r * (1.0f + sv.w));
  *(ushort4*)(p + d) = o;
}

// ---------------- fused sliding-window attention v2 -------------------------
// Fixed-max softmax (SMAX).  grid (T/64, H, B); block 256 = 4 waves.
__global__ __launch_bounds__(256) void attn_fused(
    u16* __restrict__ qkv, const u16* __restrict__ Vt) {
  const int qt = blockIdx.x, h = blockIdx.y, b = blockIdx.z;
  const int g = h & 3;                    // reference reshape => group = h % 4
  const int tid = threadIdx.x;
  const int wave = tid >> 6, lane = tid & 63;
  const int quad = lane >> 4, l16 = lane & 15;
  const int t0 = qt * 64;
  const int tw = t0 + wave * 16;
  __shared__ __align__(16) u16 Ks[2][32 * KROW];   // [kv 32][dim 256 +pad]
  __shared__ __align__(16) u16 Vs[2][256 * VROW];  // [dim 256][kv 32 +pad]
  __shared__ __align__(16) u16 Ps[4][16 * VROW];
  bf16x8 qF[8];
  {
    const u16* qrow = qkv + (size_t)(b * T_SEQ + tw + l16) * NQKV + h * 256;
#pragma unroll
    for (int kc = 0; kc < 8; ++kc)
      qF[kc] = *(const bf16x8*)(qrow + kc * 32 + quad * 8);
  }
  const u16* vt_base = Vt + (size_t)(b * 4 + g) * 256 * T_SEQ;
  const u16* k_base = qkv + (size_t)(b * T_SEQ) * NQKV + 2048 + g * 256;
  f32x4 o[16] = {};
  float lsum[4] = {0.f, 0.f, 0.f, 0.f};
  int s_lo = t0 - (WIN - 1); if (s_lo < 0) s_lo = 0; s_lo &= ~31;
  const int s_hi = t0 + 63;
  const int n_tiles = (s_hi - s_lo + 32) >> 5;

  u16x8 rK[4], rV[4];   // staged registers for next tile (static-indexed)
#define ISSUE_LOADS(sb)                                                       \
  {                                                                           \
    _Pragma("unroll")                                                         \
    for (int i = 0; i < 4; ++i) {                                             \
      int u = i * 256 + tid;                                                  \
      int krow = u >> 5, kcb = u & 31;                                        \
      rK[i] = *(const u16x8*)(k_base + (size_t)((sb) + krow) * NQKV + kcb * 8);\
      int dim = u >> 2, kvp = (u & 3) * 8;                                    \
      rV[i] = *(const u16x8*)(vt_base + (size_t)dim * T_SEQ + (sb) + kvp);    \
    }                                                                         \
  }
#define WRITE_LDS(buf)                                                        \
  {                                                                           \
    _Pragma("unroll")                                                         \
    for (int i = 0; i < 4; ++i) {                                             \
      int u = i * 256 + tid;                                                  \
      int krow = u >> 5, kcb = u & 31;                                        \
      *(u16x8*)(Ks[buf] + krow * KROW + kcb * 8) = rK[i];                     \
      int dim = u >> 2, kvp = (u & 3) * 8;                                    \
      *(u16x8*)(Vs[buf] + dim * VROW + kvp) = rV[i];                          \
    }                                                                         \
  }

  ISSUE_LOADS(s_lo);
  WRITE_LDS(0);
  __syncthreads();

  for (int ti = 0; ti < n_tiles; ++ti) {
    const int sb = s_lo + ti * 32;
    const int buf = ti & 1;
    if (ti + 1 < n_tiles) ISSUE_LOADS(sb + 32);
    // ---- QK^T: C[qrow 16][kvrow 32] ----
    f32x4 st[2] = {};
#pragma unroll
    for (int nt = 0; nt < 2; ++nt)
#pragma unroll
      for (int kc = 0; kc < 8; ++kc) {
        bf16x8 kF = *(const bf16x8*)(Ks[buf] + (nt * 16 + l16) * KROW + kc * 32 + quad * 8);
        st[nt] = __builtin_amdgcn_mfma_f32_16x16x32_bf16(qF[kc], kF, st[nt], 0, 0, 0);
      }
    // ---- fixed-max softmax: p = exp(s*scale - SMAX), masked -> 0 ----
    const bool full = (sb + 31 <= tw) && (sb >= tw + 15 - (WIN - 1));
#pragma unroll
    for (int r = 0; r < 4; ++r) {
      float v0 = st[0][r] * ATTN_SCALE - SMAX;
      float v1 = st[1][r] * ATTN_SCALE - SMAX;
      if (!full) {
        int t = tw + quad * 4 + r;
        int c0s = sb + l16, c1s = c0s + 16;
        v0 = (c0s <= t && c0s > t - WIN) ? v0 : -3.0e38f;
        v1 = (c1s <= t && c1s > t - WIN) ? v1 : -3.0e38f;
      }
      float p0 = __expf(v0);
      float p1 = __expf(v1);
      Ps[wave][(quad * 4 + r) * VROW + l16] = f2bf(p0);
      Ps[wave][(quad * 4 + r) * VROW + 16 + l16] = f2bf(p1);
      lsum[r] += p0 + p1;
    }
    // Ps is per-wave: same-wave lgkmcnt ordering suffices, no barrier.
    // ---- P·V ----
    bf16x8 pF = *(const bf16x8*)(&Ps[wave][l16 * VROW + quad * 8]);
#pragma unroll
    for (int nt = 0; nt < 16; ++nt) {
      bf16x8 vF = *(const bf16x8*)(Vs[buf] + (nt * 16 + l16) * VROW + quad * 8);
      o[nt] = __builtin_amdgcn_mfma_f32_16x16x32_bf16(pF, vF, o[nt], 0, 0, 0);
    }
    if (ti + 1 < n_tiles) WRITE_LDS(buf ^ 1);
    __syncthreads();
  }
#undef ISSUE_LOADS
#undef WRITE_LDS
#pragma unroll
  for (int r = 0; r < 4; ++r) {
    float s = lsum[r];
    s += __shfl_xor(s, 1, 64);
    s += __shfl_xor(s, 2, 64);
    s += __shfl_xor(s, 4, 64);
    s += __shfl_xor(s, 8, 64);
    lsum[r] = s;
  }
#pragma unroll
  for (int r = 0; r < 4; ++r) {
    float inv = 1.0f / lsum[r];
    int t = tw + quad * 4 + r;
    u16* orow = qkv + (size_t)(b * T_SEQ + t) * NQKV + h * 256;
#pragma unroll
    for (int nt = 0; nt < 16; ++nt)
      orow[nt * 16 + l16] = f2bf(o[nt][r] * inv);
  }
}

// ---------------------------------------------------------------------------
extern "C" void kernel_launch(void* const* d_in, const int* in_sizes, int n_in,
                              void* d_out, int out_size, void* d_ws, size_t ws_size,
                              hipStream_t stream) {
  const float* x       = (const float*)d_in[0];
  const float* Wq      = (const float*)d_in[1];
  const float* Wk      = (const float*)d_in[2];
  const float* Wv      = (const float*)d_in[3];
  const float* Wo      = (const float*)d_in[4];
  const float* q_scale = (const float*)d_in[5];
  const float* k_scale = (const float*)d_in[6];

  u16* qkv = (u16*)d_ws;                                   // 33.5 MB
  const size_t BIG_WS = (size_t)NTOK * NQKV * 2            // qkv
                      + (size_t)NTOK * D_MODEL * 2         // xbf
                      + (size_t)NQKV * D_MODEL * 2;        // WT (all QKV)

  if (ws_size >= BIG_WS) {
    // ---- big-ws path: fat-wave 256^2 GEMMs ----
    (void)hipFuncSetAttribute(reinterpret_cast<const void*>(&gemm_fat<0>),
                              hipFuncAttributeMaxDynamicSharedMemorySize, 131072);
    (void)hipFuncSetAttribute(reinterpret_cast<const void*>(&gemm_fat<1>),
                              hipFuncAttributeMaxDynamicSharedMemorySize, 131072);
    u16* xbf = qkv + (size_t)NTOK * NQKV;                  // 21 MB (later: Vt)
    u16* WT  = xbf + (size_t)NTOK * D_MODEL;               // 21 MB (later: WoT)
    cvt_f32_bf16<<<dim3(NTOK * D_MODEL / (256 * 8)), 256, 0, stream>>>(x, xbf);
    transpose_w<<<dim3(32, 40), 256, 0, stream>>>(Wq, WT, D_MODEL, 2048);
    transpose_w<<<dim3(16, 40), 256, 0, stream>>>(Wk, WT + (size_t)2048 * D_MODEL, D_MODEL, 1024);
    transpose_w<<<dim3(16, 40), 256, 0, stream>>>(Wv, WT + (size_t)3072 * D_MODEL, D_MODEL, 1024);
    gemm_fat<0><<<dim3(16, 16), 256, 131072, stream>>>(xbf, D_MODEL, WT, D_MODEL, qkv, NQKV, D_MODEL);
    rmsnorm_qk<<<dim3(12288), 256, 0, stream>>>(qkv, q_scale, k_scale);
    v_transpose<<<dim3(4, 32, 8), 256, 0, stream>>>(qkv, xbf);   // Vt in xbf slot
    attn_fused<<<dim3(T_SEQ / 64, 8, 2), 256, 0, stream>>>(qkv, xbf);
    transpose_w<<<dim3(40, 32), 256, 0, stream>>>(Wo, WT, 2048, D_MODEL);
    gemm_fat<1><<<dim3(10, 16), 256, 131072, stream>>>(qkv, NQKV, WT, 2048, d_out, D_MODEL, 2048);
  } else {
    // ---- fallback (44 MB, round-5 structure + upgraded out-proj) ----
    u16* WT = qkv + (size_t)NTOK * NQKV;                   // 10.5 MB scratch
    transpose_w<<<dim3(32, 40), 256, 0, stream>>>(Wq, WT, D_MODEL, 2048);
    gemm_f32a<<<dim3(16, 32), 256, 0, stream>>>(x, D_MODEL, WT, D_MODEL, qkv, NQKV, D_MODEL);
    transpose_w<<<dim3(16, 40), 256, 0, stream>>>(Wk, WT, D_MODEL, 1024);
    gemm_f32a<<<dim3(8, 32), 256, 0, stream>>>(x, D_MODEL, WT, D_MODEL, qkv + 2048, NQKV, D_MODEL);
    transpose_w<<<dim3(16, 40), 256, 0, stream>>>(Wv, WT, D_MODEL, 1024);
    gemm_f32a<<<dim3(8, 32), 256, 0, stream>>>(x, D_MODEL, WT, D_MODEL, qkv + 3072, NQKV, D_MODEL);
    rmsnorm_qk<<<dim3(12288), 256, 0, stream>>>(qkv, q_scale, k_scale);
    v_transpose<<<dim3(4, 32, 8), 256, 0, stream>>>(qkv, WT);
    attn_fused<<<dim3(T_SEQ / 64, 8, 2), 256, 0, stream>>>(qkv, WT);
    transpose_w<<<dim3(40, 32), 256, 0, stream>>>(Wo, WT, 2048, D_MODEL);
    gemm_fast<1><<<dim3(20, 32), 256, 0, stream>>>(qkv, NQKV, WT, 2048, d_out, D_MODEL, 2048);
  }
}

// Round 7
// 360.818 us; speedup vs baseline: 1.0807x; 1.0807x over previous
//
#include <hip/hip_runtime.h>
#include <hip/hip_bf16.h>

typedef unsigned short u16;

#define T_SEQ 2048
#define NTOK 4096          // B*T
#define D_MODEL 2560
#define NQKV 4096          // H*Hd + 2*G*Hd
#define WIN 1024
#define ATTN_SCALE 0.0625f // 256^-0.5
#define SMAX 17.0f         // |score*scale| <= 16.13 (RMSNorm => |q|=|k|=16)
#define KROW 264           // padded Ks row (u16): 528B stride -> conflict-free
#define VROW 40            // padded Vs/Ps row (u16): 80B stride -> 2-way max

typedef __attribute__((ext_vector_type(8))) short bf16x8;
typedef __attribute__((ext_vector_type(8))) unsigned short u16x8;
typedef __attribute__((ext_vector_type(4))) float f32x4;

__device__ __forceinline__ float bf2f(u16 u) {
  union { unsigned int i; float f; } c; c.i = ((unsigned int)u) << 16; return c.f;
}
__device__ __forceinline__ u16 f2bf(float f) {
  __hip_bfloat16 h = __float2bfloat16(f);
  return __builtin_bit_cast(u16, h);
}
__device__ __forceinline__ u16x8 load8f(const float* p) {
  float4 a = *(const float4*)p;
  float4 b = *(const float4*)(p + 4);
  u16x8 r;
  r[0] = f2bf(a.x); r[1] = f2bf(a.y); r[2] = f2bf(a.z); r[3] = f2bf(a.w);
  r[4] = f2bf(b.x); r[5] = f2bf(b.y); r[6] = f2bf(b.z); r[7] = f2bf(b.w);
  return r;
}
__device__ __forceinline__ void gload_lds16(const u16* g, u16* l) {
  __builtin_amdgcn_global_load_lds(
      (const __attribute__((address_space(1))) void*)g,
      (__attribute__((address_space(3))) void*)l, 16, 0, 0);
}

// ============================== device bodies ===============================
__device__ __forceinline__ void cvt_body(
    const float* __restrict__ in, u16* __restrict__ out, int bid, int t) {
  size_t i = ((size_t)bid * 256 + t) * 8;
  *(u16x8*)(out + i) = load8f(in + i);
}

// weight transpose: out[n][k] = bf16(in[k][n]); tile provided by caller
__device__ __forceinline__ void tw_body(
    const float* __restrict__ in, u16* __restrict__ out, int K, int N,
    int bx, int by, int t, u16 (*tile)[65]) {
  int kb = by * 64, nb = bx * 64;
  int c4 = (t & 15) * 4;
  int r0 = t >> 4;
#pragma unroll
  for (int i = 0; i < 4; ++i) {
    int r = r0 + i * 16;
    float4 v = *(const float4*)(in + (size_t)(kb + r) * N + nb + c4);
    tile[r][c4] = f2bf(v.x); tile[r][c4 + 1] = f2bf(v.y);
    tile[r][c4 + 2] = f2bf(v.z); tile[r][c4 + 3] = f2bf(v.w);
  }
  __syncthreads();
#pragma unroll
  for (int i = 0; i < 4; ++i) {
    int n = r0 + i * 16;
    ushort4 v;
    v.x = tile[c4 + 0][n];
    v.y = tile[c4 + 1][n];
    v.z = tile[c4 + 2][n];
    v.w = tile[c4 + 3][n];
    *(ushort4*)(out + (size_t)(nb + n) * K + kb + c4) = v;
  }
}

// V transpose: Vt[(b*4+g)][dim][t] = qkv[b,t][3072+g*256+dim]
__device__ __forceinline__ void vt_body(
    const u16* __restrict__ qkv, u16* __restrict__ Vt,
    int bx, int by, int bg, int t, u16 (*tile)[65]) {
  int b = bg >> 2, g = bg & 3;
  int tb = by * 64, db = bx * 64;
  const u16* in = qkv + (size_t)(b * T_SEQ) * NQKV + 3072 + g * 256;
  u16* out = Vt + (size_t)bg * 256 * T_SEQ;
  int c4 = (t & 15) * 4;
  int r0 = t >> 4;
#pragma unroll
  for (int i = 0; i < 4; ++i) {
    int r = r0 + i * 16;   // token within tile
    ushort4 v = *(const ushort4*)(in + (size_t)(tb + r) * NQKV + db + c4);
    tile[r][c4] = v.x; tile[r][c4 + 1] = v.y; tile[r][c4 + 2] = v.z; tile[r][c4 + 3] = v.w;
  }
  __syncthreads();
#pragma unroll
  for (int i = 0; i < 4; ++i) {
    int n = r0 + i * 16;   // dim within tile
    ushort4 v;
    v.x = tile[c4 + 0][n];
    v.y = tile[c4 + 1][n];
    v.z = tile[c4 + 2][n];
    v.w = tile[c4 + 3][n];
    *(ushort4*)(out + (size_t)(db + n) * T_SEQ + tb + c4) = v;
  }
}

__device__ __forceinline__ void rms_body(
    u16* __restrict__ qkv, const float* __restrict__ q_scale,
    const float* __restrict__ k_scale, int bid, int tidx) {
  int wv = bid * 4 + (tidx >> 6);
  int lane = tidx & 63;
  int token = wv / 12, j = wv - token * 12;
  const float* sc = (j < 8) ? q_scale : k_scale;
  int col = (j < 8) ? j * 256 : 2048 + (j - 8) * 256;
  u16* p = qkv + (size_t)token * NQKV + col;
  int d = lane * 4;
  ushort4 raw = *(const ushort4*)(p + d);
  float x0 = bf2f(raw.x), x1 = bf2f(raw.y), x2 = bf2f(raw.z), x3 = bf2f(raw.w);
  float sum = x0 * x0 + x1 * x1 + x2 * x2 + x3 * x3;
#pragma unroll
  for (int m = 1; m < 64; m <<= 1) sum += __shfl_xor(sum, m, 64);
  float r = rsqrtf(sum * (1.0f / 256.0f) + 1e-6f);
  float4 sv = *(const float4*)(sc + d);
  ushort4 o;
  o.x = f2bf(x0 * r * (1.0f + sv.x));
  o.y = f2bf(x1 * r * (1.0f + sv.y));
  o.z = f2bf(x2 * r * (1.0f + sv.z));
  o.w = f2bf(x3 * r * (1.0f + sv.w));
  *(ushort4*)(p + d) = o;
}

// ===================== merged elementwise kernels (big path) ================
// prep: cvt x->xbf (5120 blocks) + transpose Wq (1280) + Wk (640) + Wv (640)
__global__ __launch_bounds__(256) void prep(
    const float* __restrict__ x, u16* __restrict__ xbf,
    const float* __restrict__ Wq, const float* __restrict__ Wk,
    const float* __restrict__ Wv, u16* __restrict__ WT) {
  __shared__ u16 tile[64][65];
  int id = blockIdx.x, t = threadIdx.x;
  if (id < 5120) { cvt_body(x, xbf, id, t); return; }
  id -= 5120;
  if (id < 1280) { tw_body(Wq, WT, D_MODEL, 2048, id % 32, id / 32, t, tile); return; }
  id -= 1280;
  if (id < 640) { tw_body(Wk, WT + (size_t)2048 * D_MODEL, D_MODEL, 1024, id % 16, id / 16, t, tile); return; }
  id -= 640;
  tw_body(Wv, WT + (size_t)3072 * D_MODEL, D_MODEL, 1024, id % 16, id / 16, t, tile);
}

// post: rmsnorm q/k (12288) + v_transpose (1024) + transpose Wo->WT (1280)
// independence: rmsnorm touches qkv cols 0..3071; v_transpose reads cols
// 3072..4095 and writes Vt (xbf slot, QKV gemm done); Wo-transpose writes WT
// (QKV gemm done).
__global__ __launch_bounds__(256) void post(
    u16* __restrict__ qkv, const float* __restrict__ q_scale,
    const float* __restrict__ k_scale, u16* __restrict__ Vt,
    const float* __restrict__ Wo, u16* __restrict__ WT) {
  __shared__ u16 tile[64][65];
  int id = blockIdx.x, t = threadIdx.x;
  if (id < 12288) { rms_body(qkv, q_scale, k_scale, id, t); return; }
  id -= 12288;
  if (id < 1024) { vt_body(qkv, Vt, id & 3, (id >> 2) & 31, id >> 7, t, tile); return; }
  id -= 1024;
  tw_body(Wo, WT, 2048, D_MODEL, id % 40, id / 40, t, tile);
}

// ============ standalone kernels (fallback path) ============================
__global__ __launch_bounds__(256) void transpose_w(
    const float* __restrict__ in, u16* __restrict__ out, int K, int N) {
  __shared__ u16 tile[64][65];
  tw_body(in, out, K, N, blockIdx.x, blockIdx.y, threadIdx.x, tile);
}
__global__ __launch_bounds__(256) void v_transpose(
    const u16* __restrict__ qkv, u16* __restrict__ Vt) {
  __shared__ u16 tile[64][65];
  vt_body(qkv, Vt, blockIdx.x, blockIdx.y, blockIdx.z, threadIdx.x, tile);
}
__global__ __launch_bounds__(256) void rmsnorm_qk(
    u16* __restrict__ qkv, const float* __restrict__ q_scale,
    const float* __restrict__ k_scale) {
  rms_body(qkv, q_scale, k_scale, blockIdx.x, threadIdx.x);
}

// ============================================================================
// gemm_256 (round-2 body -- best measured 86.8-87.2us): 256x256 tile, 512
// threads (8 waves, 2M x 4N), BK=32 ring-of-4 LDS + aA register prefetch,
// 2 barriers/K-step, counted vmcnt, XOR-swizzled LDS, XCD-chunked swizzle.
// ============================================================================
template <int WC>
__global__ __launch_bounds__(512, 2) void gemm_256(
    const u16* __restrict__ A, int lda, const u16* __restrict__ Bt, int ldb,
    void* __restrict__ C, int ldc, int K) {
  extern __shared__ ulong2 LDSraw[];
  u16* SA = (u16*)LDSraw;          // [4][8192]
  u16* SB = SA + 32768;            // [4][8192]
  const int tid = threadIdx.x;
  const int wave = tid >> 6, lane = tid & 63;
  const int quad = lane >> 4, l16 = lane & 15;
  const int gx = gridDim.x;
  const int orig = blockIdx.y * gx + blockIdx.x;
  const int cpx = (gx * gridDim.y) >> 3;
  const int swz = (orig & 7) * cpx + (orig >> 3);
  const int mblk = (swz / gx) * 256, nblk = (swz % gx) * 256;
  const int wm = (wave >> 2) * 128, wn = (wave & 3) * 64;

  const u16* srcA[2]; const u16* srcB[2];
  int ldsOff[2];
#pragma unroll
  for (int i = 0; i < 2; ++i) {
    int u = i * 512 + tid;
    int hi3 = (u & 7) ^ ((u >> 3) & 7);
    int r = ((u >> 3) << 1) | (hi3 >> 2);
    int cbe = (hi3 & 3) << 3;
    srcA[i] = A + (size_t)(mblk + r) * lda + cbe;
    srcB[i] = Bt + (size_t)(nblk + r) * ldb + cbe;
    ldsOff[i] = (u >> 6) << 9;     // wave-uniform (u>>6 = i*8 + wave)
  }
  const int unit = ((((l16 & 1) << 2) | quad) ^ ((l16 >> 1) & 7)) << 3;
  const int base_a = ((wm >> 1) + (l16 >> 1)) * 64 + unit;
  const int base_b = ((wn >> 1) + (l16 >> 1)) * 64 + unit;
  const int NK = K >> 5;
  f32x4 acc[8][4] = {};

  auto stage = [&](int s, int i) {
    int slot = s & 3;
    gload_lds16(srcA[i] + s * 32, SA + slot * 8192 + ldsOff[i]);
    gload_lds16(srcB[i] + s * 32, SB + slot * 8192 + ldsOff[i]);
  };

  stage(0, 0); stage(0, 1); stage(1, 0); stage(1, 1); stage(2, 0); stage(2, 1);
  asm volatile("s_waitcnt vmcnt(8)" ::: "memory");
  __builtin_amdgcn_s_barrier();
  asm volatile("" ::: "memory");

  bf16x8 aA[4], aB[4], bF[4];
#pragma unroll
  for (int t = 0; t < 4; ++t) aA[t] = *(const bf16x8*)(SA + base_a + t * 512);

  for (int s = 0; s < NK; ++s) {
    const u16* sa = SA + (s & 3) * 8192;
    const u16* sb = SB + (s & 3) * 8192;
    // ---- phase A: issue bF(s) (exposed) + aB(s) (hidden); MFMA on aA(s) ----
#pragma unroll
    for (int t = 0; t < 4; ++t) bF[t] = *(const bf16x8*)(sb + base_b + t * 512);
#pragma unroll
    for (int t = 0; t < 4; ++t) aB[t] = *(const bf16x8*)(sa + base_a + (t + 4) * 512);
    if (s + 3 < NK) stage(s + 3, 0);
    __builtin_amdgcn_s_setprio(1);
#pragma unroll
    for (int n = 0; n < 4; ++n)
#pragma unroll
      for (int m = 0; m < 4; ++m)
        acc[m][n] = __builtin_amdgcn_mfma_f32_16x16x32_bf16(aA[m], bF[n], acc[m][n], 0, 0, 0);
    __builtin_amdgcn_s_setprio(0);
    if (s < NK - 3)       asm volatile("s_waitcnt vmcnt(6)" ::: "memory");
    else if (s == NK - 3) asm volatile("s_waitcnt vmcnt(4)" ::: "memory");
    else if (s == NK - 2) asm volatile("s_waitcnt vmcnt(0)" ::: "memory");
    __builtin_amdgcn_s_barrier();
    asm volatile("" ::: "memory");
    // ---- phase B: issue aA(s+1) (hidden); MFMA on aB(s) ----
    if (s + 1 < NK) {
      const u16* sn = SA + ((s + 1) & 3) * 8192;
#pragma unroll
      for (int t = 0; t < 4; ++t) aA[t] = *(const bf16x8*)(sn + base_a + t * 512);
    }
    if (s + 3 < NK) stage(s + 3, 1);
    __builtin_amdgcn_s_setprio(1);
#pragma unroll
    for (int n = 0; n < 4; ++n)
#pragma unroll
      for (int m = 0; m < 4; ++m)
        acc[m + 4][n] = __builtin_amdgcn_mfma_f32_16x16x32_bf16(aB[m], bF[n], acc[m + 4][n], 0, 0, 0);
    __builtin_amdgcn_s_setprio(0);
    if (s + 1 < NK) {
      asm volatile("" ::: "memory");
      __builtin_amdgcn_s_barrier();
      asm volatile("" ::: "memory");
    }
  }
#pragma unroll
  for (int m = 0; m < 8; ++m)
#pragma unroll
    for (int n = 0; n < 4; ++n)
#pragma unroll
      for (int r = 0; r < 4; ++r) {
        int row = mblk + wm + m * 16 + quad * 4 + r;
        int col = nblk + wn + n * 16 + l16;
        if constexpr (WC)
          ((float*)C)[(size_t)row * ldc + col] = acc[m][n][r];
        else
          ((u16*)C)[(size_t)row * ldc + col] = f2bf(acc[m][n][r]);
      }
}

// ---------------- fast GEMM (m97): bf16 A/Bt, global_load_lds staging -------
// Used for the out-projection (640-block grid -> full chip fill).
template <int WC>
__global__ __launch_bounds__(256, 2) void gemm_fast(
    const u16* __restrict__ A, int lda, const u16* __restrict__ Bt, int ldb,
    void* __restrict__ C, int ldc, int K) {
  __shared__ __align__(16) u16 As[128 * 32];
  __shared__ __align__(16) u16 Bs[128 * 32];
  const int tid = threadIdx.x;
  const int wave = tid >> 6, lane = tid & 63;
  const int quad = lane >> 4, l16 = lane & 15;
  const int mblk = blockIdx.y * 128, nblk = blockIdx.x * 128;
  const int wm = (wave >> 1) * 64, wn = (wave & 1) * 64;
  f32x4 acc[4][4] = {};
  const int c0 = wave * 2;
  for (int k0 = 0; k0 < K; k0 += 32) {
#pragma unroll
    for (int i = 0; i < 2; ++i) {
      int c = c0 + i;
      int flat = c * 64 + lane;       // 16B unit 0..511
      int row = flat >> 2;
      int kb = (flat & 3) * 8;
      gload_lds16(A + (size_t)(mblk + row) * lda + k0 + kb, As + c * 512);
      gload_lds16(Bt + (size_t)(nblk + row) * ldb + k0 + kb, Bs + c * 512);
    }
    __syncthreads();
    bf16x8 aF[4], bF[4];
#pragma unroll
    for (int t = 0; t < 4; ++t) {
      aF[t] = *(const bf16x8*)(As + (wm + t * 16 + l16) * 32 + quad * 8);
      bF[t] = *(const bf16x8*)(Bs + (wn + t * 16 + l16) * 32 + quad * 8);
    }
#pragma unroll
    for (int tm = 0; tm < 4; ++tm)
#pragma unroll
      for (int tn = 0; tn < 4; ++tn)
        acc[tm][tn] = __builtin_amdgcn_mfma_f32_16x16x32_bf16(aF[tm], bF[tn], acc[tm][tn], 0, 0, 0);
    __syncthreads();
  }
#pragma unroll
  for (int tm = 0; tm < 4; ++tm)
#pragma unroll
    for (int tn = 0; tn < 4; ++tn)
#pragma unroll
      for (int r = 0; r < 4; ++r) {
        int row = mblk + wm + tm * 16 + quad * 4 + r;
        int col = nblk + wn + tn * 16 + l16;
        if constexpr (WC)
          ((float*)C)[(size_t)row * ldc + col] = acc[tm][tn][r];
        else
          ((u16*)C)[(size_t)row * ldc + col] = f2bf(acc[tm][tn][r]);
      }
}

// ---------------- fallback GEMM: f32 A, manual staging ----------------------
__global__ __launch_bounds__(256, 2) void gemm_f32a(
    const float* __restrict__ A, int lda, const u16* __restrict__ Bt, int ldb,
    u16* __restrict__ C, int ldc, int K) {
  __shared__ __align__(16) u16 As[128 * 32];
  __shared__ __align__(16) u16 Bs[128 * 32];
  const int tid = threadIdx.x;
  const int wave = tid >> 6, lane = tid & 63;
  const int quad = lane >> 4, l16 = lane & 15;
  const int mblk = blockIdx.y * 128, nblk = blockIdx.x * 128;
  const int wm = (wave >> 1) * 64, wn = (wave & 1) * 64;
  f32x4 acc[4][4] = {};
  for (int k0 = 0; k0 < K; k0 += 32) {
#pragma unroll
    for (int i = 0; i < 2; ++i) {
      int u = i * 256 + tid;
      int row = u >> 2;
      int kb = (u & 3) * 8;
      *(u16x8*)(As + row * 32 + kb) = load8f(A + (size_t)(mblk + row) * lda + k0 + kb);
      *(u16x8*)(Bs + row * 32 + kb) = *(const u16x8*)(Bt + (size_t)(nblk + row) * ldb + k0 + kb);
    }
    __syncthreads();
    bf16x8 aF[4], bF[4];
#pragma unroll
    for (int t = 0; t < 4; ++t) {
      aF[t] = *(const bf16x8*)(As + (wm + t * 16 + l16) * 32 + quad * 8);
      bF[t] = *(const bf16x8*)(Bs + (wn + t * 16 + l16) * 32 + quad * 8);
    }
#pragma unroll
    for (int tm = 0; tm < 4; ++tm)
#pragma unroll
      for (int tn = 0; tn < 4; ++tn)
        acc[tm][tn] = __builtin_amdgcn_mfma_f32_16x16x32_bf16(aF[tm], bF[tn], acc[tm][tn], 0, 0, 0);
    __syncthreads();
  }
#pragma unroll
  for (int tm = 0; tm < 4; ++tm)
#pragma unroll
    for (int tn = 0; tn < 4; ++tn)
#pragma unroll
      for (int r = 0; r < 4; ++r) {
        int row = mblk + wm + tm * 16 + quad * 4 + r;
        int col = nblk + wn + tn * 16 + l16;
        C[(size_t)row * ldc + col] = f2bf(acc[tm][tn][r]);
      }
}

// ---------------- fused sliding-window attention v2 -------------------------
// Fixed-max softmax (SMAX).  grid (T/64, H, B); block 256 = 4 waves.
__global__ __launch_bounds__(256) void attn_fused(
    u16* __restrict__ qkv, const u16* __restrict__ Vt) {
  const int qt = blockIdx.x, h = blockIdx.y, b = blockIdx.z;
  const int g = h & 3;                    // reference reshape => group = h % 4
  const int tid = threadIdx.x;
  const int wave = tid >> 6, lane = tid & 63;
  const int quad = lane >> 4, l16 = lane & 15;
  const int t0 = qt * 64;
  const int tw = t0 + wave * 16;
  __shared__ __align__(16) u16 Ks[2][32 * KROW];   // [kv 32][dim 256 +pad]
  __shared__ __align__(16) u16 Vs[2][256 * VROW];  // [dim 256][kv 32 +pad]
  __shared__ __align__(16) u16 Ps[4][16 * VROW];
  bf16x8 qF[8];
  {
    const u16* qrow = qkv + (size_t)(b * T_SEQ + tw + l16) * NQKV + h * 256;
#pragma unroll
    for (int kc = 0; kc < 8; ++kc)
      qF[kc] = *(const bf16x8*)(qrow + kc * 32 + quad * 8);
  }
  const u16* vt_base = Vt + (size_t)(b * 4 + g) * 256 * T_SEQ;
  const u16* k_base = qkv + (size_t)(b * T_SEQ) * NQKV + 2048 + g * 256;
  f32x4 o[16] = {};
  float lsum[4] = {0.f, 0.f, 0.f, 0.f};
  int s_lo = t0 - (WIN - 1); if (s_lo < 0) s_lo = 0; s_lo &= ~31;
  const int s_hi = t0 + 63;
  const int n_tiles = (s_hi - s_lo + 32) >> 5;

  u16x8 rK[4], rV[4];   // staged registers for next tile (static-indexed)
#define ISSUE_LOADS(sb)                                                       \
  {                                                                           \
    _Pragma("unroll")                                                         \
    for (int i = 0; i < 4; ++i) {                                             \
      int u = i * 256 + tid;                                                  \
      int krow = u >> 5, kcb = u & 31;                                        \
      rK[i] = *(const u16x8*)(k_base + (size_t)((sb) + krow) * NQKV + kcb * 8);\
      int dim = u >> 2, kvp = (u & 3) * 8;                                    \
      rV[i] = *(const u16x8*)(vt_base + (size_t)dim * T_SEQ + (sb) + kvp);    \
    }                                                                         \
  }
#define WRITE_LDS(buf)                                                        \
  {                                                                           \
    _Pragma("unroll")                                                         \
    for (int i = 0; i < 4; ++i) {                                             \
      int u = i * 256 + tid;                                                  \
      int krow = u >> 5, kcb = u & 31;                                        \
      *(u16x8*)(Ks[buf] + krow * KROW + kcb * 8) = rK[i];                     \
      int dim = u >> 2, kvp = (u & 3) * 8;                                    \
      *(u16x8*)(Vs[buf] + dim * VROW + kvp) = rV[i];                          \
    }                                                                         \
  }

  ISSUE_LOADS(s_lo);
  WRITE_LDS(0);
  __syncthreads();

  for (int ti = 0; ti < n_tiles; ++ti) {
    const int sb = s_lo + ti * 32;
    const int buf = ti & 1;
    if (ti + 1 < n_tiles) ISSUE_LOADS(sb + 32);
    // ---- QK^T: C[qrow 16][kvrow 32] ----
    f32x4 st[2] = {};
#pragma unroll
    for (int nt = 0; nt < 2; ++nt)
#pragma unroll
      for (int kc = 0; kc < 8; ++kc) {
        bf16x8 kF = *(const bf16x8*)(Ks[buf] + (nt * 16 + l16) * KROW + kc * 32 + quad * 8);
        st[nt] = __builtin_amdgcn_mfma_f32_16x16x32_bf16(qF[kc], kF, st[nt], 0, 0, 0);
      }
    // ---- fixed-max softmax: p = exp(s*scale - SMAX), masked -> 0 ----
    const bool full = (sb + 31 <= tw) && (sb >= tw + 15 - (WIN - 1));
#pragma unroll
    for (int r = 0; r < 4; ++r) {
      float v0 = st[0][r] * ATTN_SCALE - SMAX;
      float v1 = st[1][r] * ATTN_SCALE - SMAX;
      if (!full) {
        int t = tw + quad * 4 + r;
        int c0s = sb + l16, c1s = c0s + 16;
        v0 = (c0s <= t && c0s > t - WIN) ? v0 : -3.0e38f;
        v1 = (c1s <= t && c1s > t - WIN) ? v1 : -3.0e38f;
      }
      float p0 = __expf(v0);
      float p1 = __expf(v1);
      Ps[wave][(quad * 4 + r) * VROW + l16] = f2bf(p0);
      Ps[wave][(quad * 4 + r) * VROW + 16 + l16] = f2bf(p1);
      lsum[r] += p0 + p1;
    }
    // Ps is per-wave: same-wave lgkmcnt ordering suffices, no barrier.
    // ---- P·V ----
    bf16x8 pF = *(const bf16x8*)(&Ps[wave][l16 * VROW + quad * 8]);
#pragma unroll
    for (int nt = 0; nt < 16; ++nt) {
      bf16x8 vF = *(const bf16x8*)(Vs[buf] + (nt * 16 + l16) * VROW + quad * 8);
      o[nt] = __builtin_amdgcn_mfma_f32_16x16x32_bf16(pF, vF, o[nt], 0, 0, 0);
    }
    if (ti + 1 < n_tiles) WRITE_LDS(buf ^ 1);
    __syncthreads();
  }
#undef ISSUE_LOADS
#undef WRITE_LDS
#pragma unroll
  for (int r = 0; r < 4; ++r) {
    float s = lsum[r];
    s += __shfl_xor(s, 1, 64);
    s += __shfl_xor(s, 2, 64);
    s += __shfl_xor(s, 4, 64);
    s += __shfl_xor(s, 8, 64);
    lsum[r] = s;
  }
#pragma unroll
  for (int r = 0; r < 4; ++r) {
    float inv = 1.0f / lsum[r];
    int t = tw + quad * 4 + r;
    u16* orow = qkv + (size_t)(b * T_SEQ + t) * NQKV + h * 256;
#pragma unroll
    for (int nt = 0; nt < 16; ++nt)
      orow[nt * 16 + l16] = f2bf(o[nt][r] * inv);
  }
}

// ---------------------------------------------------------------------------
extern "C" void kernel_launch(void* const* d_in, const int* in_sizes, int n_in,
                              void* d_out, int out_size, void* d_ws, size_t ws_size,
                              hipStream_t stream) {
  const float* x       = (const float*)d_in[0];
  const float* Wq      = (const float*)d_in[1];
  const float* Wk      = (const float*)d_in[2];
  const float* Wv      = (const float*)d_in[3];
  const float* Wo      = (const float*)d_in[4];
  const float* q_scale = (const float*)d_in[5];
  const float* k_scale = (const float*)d_in[6];

  u16* qkv = (u16*)d_ws;                                   // 33.5 MB
  const size_t BIG_WS = (size_t)NTOK * NQKV * 2            // qkv
                      + (size_t)NTOK * D_MODEL * 2         // xbf
                      + (size_t)NQKV * D_MODEL * 2;        // WT (all QKV)

  if (ws_size >= BIG_WS) {
    // ---- big-ws path: 5 launches total ----
    (void)hipFuncSetAttribute(reinterpret_cast<const void*>(&gemm_256<0>),
                              hipFuncAttributeMaxDynamicSharedMemorySize, 131072);
    u16* xbf = qkv + (size_t)NTOK * NQKV;                  // 21 MB (later: Vt)
    u16* WT  = xbf + (size_t)NTOK * D_MODEL;               // 21 MB
    // 1) cvt + Wq/Wk/Wv transposes (disjoint outputs)
    prep<<<dim3(5120 + 1280 + 640 + 640), 256, 0, stream>>>(x, xbf, Wq, Wk, Wv, WT);
    // 2) QKV projection
    gemm_256<0><<<dim3(16, 16), 512, 131072, stream>>>(xbf, D_MODEL, WT, D_MODEL, qkv, NQKV, D_MODEL);
    // 3) rmsnorm + v_transpose (Vt in xbf slot) + Wo transpose (WT free now)
    post<<<dim3(12288 + 1024 + 1280), 256, 0, stream>>>(qkv, q_scale, k_scale, xbf, Wo, WT);
    // 4) fused attention (in-place over Q region)
    attn_fused<<<dim3(T_SEQ / 64, 8, 2), 256, 0, stream>>>(qkv, xbf);
    // 5) out-projection
    gemm_fast<1><<<dim3(20, 32), 256, 0, stream>>>(qkv, NQKV, WT, 2048, d_out, D_MODEL, 2048);
  } else {
    // ---- fallback (44 MB) ----
    u16* WT = qkv + (size_t)NTOK * NQKV;                   // 10.5 MB scratch
    transpose_w<<<dim3(32, 40), 256, 0, stream>>>(Wq, WT, D_MODEL, 2048);
    gemm_f32a<<<dim3(16, 32), 256, 0, stream>>>(x, D_MODEL, WT, D_MODEL, qkv, NQKV, D_MODEL);
    transpose_w<<<dim3(16, 40), 256, 0, stream>>>(Wk, WT, D_MODEL, 1024);
    gemm_f32a<<<dim3(8, 32), 256, 0, stream>>>(x, D_MODEL, WT, D_MODEL, qkv + 2048, NQKV, D_MODEL);
    transpose_w<<<dim3(16, 40), 256, 0, stream>>>(Wv, WT, D_MODEL, 1024);
    gemm_f32a<<<dim3(8, 32), 256, 0, stream>>>(x, D_MODEL, WT, D_MODEL, qkv + 3072, NQKV, D_MODEL);
    rmsnorm_qk<<<dim3(12288), 256, 0, stream>>>(qkv, q_scale, k_scale);
    v_transpose<<<dim3(4, 32, 8), 256, 0, stream>>>(qkv, WT);
    attn_fused<<<dim3(T_SEQ / 64, 8, 2), 256, 0, stream>>>(qkv, WT);
    transpose_w<<<dim3(40, 32), 256, 0, stream>>>(Wo, WT, 2048, D_MODEL);
    gemm_fast<1><<<dim3(20, 32), 256, 0, stream>>>(qkv, NQKV, WT, 2048, d_out, D_MODEL, 2048);
  }
}